// Round 6
// baseline (392.932 us; speedup 1.0000x reference)
//
#include <hip/hip_runtime.h>
#include <math.h>

#define DTC 0.1f

typedef _Float16 half8 __attribute__((ext_vector_type(8)));
typedef _Float16 half4v __attribute__((ext_vector_type(4)));
typedef float f32x4 __attribute__((ext_vector_type(4)));

__device__ __forceinline__ float fast_tanh(float x) {
  const float e = __expf(2.f * x);
  const float r = __builtin_amdgcn_rcpf(e + 1.f);
  return fmaf(-2.f, r, 1.f);
}

// ================= precompute =================================================

// Wh = fp16(W) ; Wt = fp16(W^T) ; crm[l][j] = -0.09 * sum_k b_{l+2}[k] W_l[k][j]
__global__ __launch_bounds__(256) void k_prep(
    const float* __restrict__ W0, const float* __restrict__ W1,
    const float* __restrict__ W2, const float* __restrict__ W3,
    const float* __restrict__ b2, const float* __restrict__ b3,
    const float* __restrict__ b4,
    _Float16* __restrict__ Wh, _Float16* __restrict__ Wt,
    float* __restrict__ crm) {
  const float* Ws[4] = {W0, W1, W2, W3};
  const int bid = blockIdx.x, tid = threadIdx.x;
  if (bid < 128) {
    const int t = bid * 256 + tid;
    const float* W = Ws[(t * 8) >> 16];
    const int off = (t * 8) & 65535;
    const float4 a = *(const float4*)&W[off];
    const float4 b = *(const float4*)&W[off + 4];
    half8 h;
    h[0] = (_Float16)a.x; h[1] = (_Float16)a.y; h[2] = (_Float16)a.z; h[3] = (_Float16)a.w;
    h[4] = (_Float16)b.x; h[5] = (_Float16)b.y; h[6] = (_Float16)b.z; h[7] = (_Float16)b.w;
    *(half8*)&Wh[t * 8] = h;
  } else if (bid < 384) {
    __shared__ float sh[32][33];
    const int b2i = bid - 128;
    const int l = b2i >> 6, t64 = b2i & 63;
    const int r0 = (t64 >> 3) * 32, c0 = (t64 & 7) * 32;
    const float* W = Ws[l];
    const int i = tid >> 5, j = tid & 31;
#pragma unroll
    for (int p = 0; p < 4; ++p)
      sh[p * 8 + i][j] = W[(r0 + p * 8 + i) * 256 + c0 + j];
    __syncthreads();
#pragma unroll
    for (int p = 0; p < 4; ++p)
      Wt[l * 65536 + (c0 + p * 8 + i) * 256 + r0 + j] = (_Float16)sh[j][p * 8 + i];
  } else {
    const int l = bid - 384;
    const float* W = Ws[l];
    const float* b = (l == 0) ? b2 : (l == 1) ? b3 : b4;
    float s = 0.f;
#pragma unroll 8
    for (int k = 0; k < 256; ++k) s = fmaf(b[k], W[k * 256 + tid], s);
    crm[l * 256 + tid] = -0.09f * s;
  }
}

// C = scale*(A@B^T) [+ I - Eadd]   per layer (blockIdx.z), 256x256, fp16 rm out
__global__ __launch_bounds__(256) void k_smm3(const _Float16* __restrict__ A,
                                              const _Float16* __restrict__ B,
                                              const _Float16* __restrict__ Eadd,
                                              _Float16* __restrict__ C,
                                              float scale, int addI) {
  const int tid = threadIdx.x, wave = tid >> 6, lane = tid & 63;
  const int quad = lane >> 4, l16 = lane & 15;
  const int l = blockIdx.z;
  const _Float16* Al = A + (size_t)l * 65536;
  const _Float16* Bl = B + (size_t)l * 65536;
  _Float16* Cl = C + (size_t)l * 65536;
  const int m0 = blockIdx.y * 64 + wave * 16, n0 = blockIdx.x * 64;
  f32x4 acc[4] = {};
#pragma unroll
  for (int kt = 0; kt < 8; ++kt) {
    const half8 af = *(const half8*)&Al[(m0 + l16) * 256 + kt * 32 + quad * 8];
#pragma unroll
    for (int ni = 0; ni < 4; ++ni) {
      const half8 bf = *(const half8*)&Bl[(n0 + ni * 16 + l16) * 256 + kt * 32 + quad * 8];
      acc[ni] = __builtin_amdgcn_mfma_f32_16x16x32_f16(af, bf, acc[ni], 0, 0, 0);
    }
  }
#pragma unroll
  for (int ni = 0; ni < 4; ++ni)
#pragma unroll
    for (int r = 0; r < 4; ++r) {
      const int row = m0 + quad * 4 + r, col = n0 + ni * 16 + l16;
      float v = scale * acc[ni][r];
      if (addI) v += (row == col ? 1.f : 0.f) - (float)(Eadd + (size_t)l * 65536)[row * 256 + col];
      Cl[row * 256 + col] = (_Float16)v;
    }
}

// Destination-mapped coalesced packing of all B-frag weight buffers.
// packed idx = ((ntile*NKT+kt)*64 + lane)*8 + j
// holds B[n=ntile*16+(lane&15)][k=kt*32+(lane>>4)*8+j]
__global__ __launch_bounds__(256) void k_pack(
    const _Float16* __restrict__ Ph, const _Float16* __restrict__ Qt,
    const _Float16* __restrict__ Wt, const float* __restrict__ Wi,
    const float* __restrict__ Wo,
    _Float16* __restrict__ PQP, _Float16* __restrict__ RmP,
    _Float16* __restrict__ WiP, _Float16* __restrict__ WoP) {
  const int t = blockIdx.x * 256 + threadIdx.x;
  if (t < 65536) {  // PQP: NKT=16, kt<8 -> -P (sym), kt>=8 -> Qt
    const int l = t >> 14, c = t & 16383;
    const int ntile = c >> 10, kt = (c >> 6) & 15, lb = c & 63;
    const int n = ntile * 16 + (lb & 15);
    const int kq = (lb >> 4) * 8;
    half8 h;
    if (kt < 8) {
      h = *(const half8*)&Ph[(size_t)l * 65536 + n * 256 + kt * 32 + kq];
#pragma unroll
      for (int j = 0; j < 8; ++j) h[j] = -h[j];
    } else {
      h = *(const half8*)&Qt[(size_t)l * 65536 + n * 256 + (kt - 8) * 32 + kq];
    }
    *(half8*)&PQP[(size_t)t * 8] = h;
  } else if (t < 90112) {  // RmP: NKT=8, B[n][k] = -0.9*Wt[n][k]
    const int tt = t - 65536;
    const int l = tt >> 13, c = tt & 8191;
    const int ntile = c >> 9, kt = (c >> 6) & 7, lb = c & 63;
    const int n = ntile * 16 + (lb & 15);
    const int k0 = kt * 32 + (lb >> 4) * 8;
    half8 h = *(const half8*)&Wt[(size_t)l * 65536 + n * 256 + k0];
#pragma unroll
    for (int j = 0; j < 8; ++j) h[j] = (_Float16)(-0.9f * (float)h[j]);
    *(half8*)&RmP[(size_t)tt * 8] = h;
  } else if (t < 98304) {  // WiP: NKT=8, B[n][k] = Wi[n][k]
    const int c = t - 90112;
    const int ntile = c >> 9, kt = (c >> 6) & 7, lb = c & 63;
    const int n = ntile * 16 + (lb & 15);
    const int k0 = kt * 32 + (lb >> 4) * 8;
    const float4 a = *(const float4*)&Wi[n * 256 + k0];
    const float4 b = *(const float4*)&Wi[n * 256 + k0 + 4];
    half8 h;
    h[0] = (_Float16)a.x; h[1] = (_Float16)a.y; h[2] = (_Float16)a.z; h[3] = (_Float16)a.w;
    h[4] = (_Float16)b.x; h[5] = (_Float16)b.y; h[6] = (_Float16)b.z; h[7] = (_Float16)b.w;
    *(half8*)&WiP[(size_t)c * 8] = h;
  } else {  // WoP: NKT=8, classes padded to 16
    const int c = t - 98304;  // 0..511
    const int kt = c >> 6, lb = c & 63;
    const int n = lb & 15;
    const int k0 = kt * 32 + (lb >> 4) * 8;
    half8 h;
#pragma unroll
    for (int j = 0; j < 8; ++j) h[j] = (_Float16)((n < 10) ? Wo[n * 256 + k0 + j] : 0.f);
    *(half8*)&WoP[(size_t)c * 8] = h;
  }
}

// ================= fused persistent batch kernel =============================
// 128-thread blocks (2 waves), 32 batch rows per block. Wave w computes cols
// [w*128, w*128+128). r1/r2 live in two 16 KB LDS slabs (32 rows x 256 cols,
// fp16, XOR-swizzled 16B chunks). Weights read as packed B-frags from L2.
// Small barrier scope (2 waves) + ~4 blocks/CU -> epilogue/MFMA overlap
// across blocks. No private arrays that can demote to scratch.

__device__ __forceinline__ void lds_w16h(_Float16* base, int row, int col, _Float16 v) {
  const int chunk = (col >> 3) ^ (row & 7);
  *(_Float16*)((char*)base + row * 512 + (chunk << 4) + (col & 7) * 2) = v;
}
__device__ __forceinline__ float lds_r16h(const _Float16* base, int row, int col) {
  const int chunk = (col >> 3) ^ (row & 7);
  return (float)*(const _Float16*)((const char*)base + row * 512 + (chunk << 4) + (col & 7) * 2);
}

// acc[mi*8+ni]: mi in {0,1} (rows mi*16..), ni in {0..7} (cols w*128+ni*16..)
template <int NKT, bool DUAL>
__device__ __forceinline__ void gemm_k(const _Float16* __restrict__ Bp,
                                       const _Float16* __restrict__ Aa,
                                       const _Float16* __restrict__ Ab,
                                       f32x4 (&acc)[16], int w, int lane,
                                       int quad, int l16) {
  half8 cb[8], nb[8];
#pragma unroll
  for (int ni = 0; ni < 8; ++ni)
    cb[ni] = *(const half8*)&Bp[(size_t)(((w * 8 + ni) * NKT) * 64 + lane) * 8];
#pragma unroll
  for (int kt = 0; kt < NKT; ++kt) {
    if (kt + 1 < NKT) {
#pragma unroll
      for (int ni = 0; ni < 8; ++ni)
        nb[ni] = *(const half8*)&Bp[(size_t)(((w * 8 + ni) * NKT + kt + 1) * 64 + lane) * 8];
    }
    const _Float16* As = (DUAL && kt >= NKT / 2) ? Ab : Aa;
    const int akt = DUAL ? (kt % (NKT / 2)) : kt;
    const int r0 = l16, r1 = 16 + l16;
    const half8 af0 = *(const half8*)((const char*)As + r0 * 512 +
                                      (((akt * 4 + quad) ^ (r0 & 7)) << 4));
    const half8 af1 = *(const half8*)((const char*)As + r1 * 512 +
                                      (((akt * 4 + quad) ^ (r1 & 7)) << 4));
#pragma unroll
    for (int ni = 0; ni < 8; ++ni) {
      acc[ni]     = __builtin_amdgcn_mfma_f32_16x16x32_f16(af0, cb[ni], acc[ni], 0, 0, 0);
      acc[8 + ni] = __builtin_amdgcn_mfma_f32_16x16x32_f16(af1, cb[ni], acc[8 + ni], 0, 0, 0);
    }
    if (kt + 1 < NKT) {
#pragma unroll
      for (int ni = 0; ni < 8; ++ni) cb[ni] = nb[ni];
    }
  }
}

__global__ __launch_bounds__(128, 2) void k_fused(
    const float* __restrict__ x, const _Float16* __restrict__ WiP,
    const _Float16* __restrict__ PQP, const _Float16* __restrict__ RmP,
    const _Float16* __restrict__ WoP, const float* __restrict__ bi,
    const float* __restrict__ b1, const float* __restrict__ b2,
    const float* __restrict__ b3, const float* __restrict__ b4,
    const float* __restrict__ crm, const float* __restrict__ bo,
    float* __restrict__ out) {
  __shared__ __align__(16) _Float16 R1[32 * 256];
  __shared__ __align__(16) _Float16 R2[32 * 256];
  const int tid = threadIdx.x;
  const int w = tid >> 6, lane = tid & 63;
  const int quad = lane >> 4, l16 = lane & 15;
  const int m0 = blockIdx.x * 32;

  // ---- stage x rows [m0, m0+32): wave w stages rows w*16..w*16+15 into R1 ----
#pragma unroll
  for (int it = 0; it < 16; ++it) {
    const int row = w * 16 + it;
    const float4 v = *(const float4*)&x[(size_t)(m0 + row) * 256 + lane * 4];
    const int chunk = (lane >> 1) ^ (row & 7), part = lane & 1;
    _Float16* p = (_Float16*)((char*)R1 + row * 512 + (chunk << 4) + (part << 3));
    p[0] = (_Float16)v.x; p[1] = (_Float16)v.y; p[2] = (_Float16)v.z; p[3] = (_Float16)v.w;
  }
  __syncthreads();

  f32x4 acc[16];
  const f32x4 zero = {0.f, 0.f, 0.f, 0.f};

  // ---- GEMM0: z = x@WiT ; R1 = r1 = z+bi+0.1*b1 ; R2 = r2 = tanh(z+bi) ----
#pragma unroll
  for (int t = 0; t < 16; ++t) acc[t] = zero;
  gemm_k<8, false>(WiP, R1, R1, acc, w, lane, quad, l16);
  __syncthreads();
#pragma unroll
  for (int ni = 0; ni < 8; ++ni) {
    const int col = w * 128 + ni * 16 + l16;
    const float bic = bi[col], b1c = DTC * b1[col];
#pragma unroll
    for (int mi = 0; mi < 2; ++mi)
#pragma unroll
      for (int r = 0; r < 4; ++r) {
        const int row = mi * 16 + quad * 4 + r;
        const float z = acc[mi * 8 + ni][r] + bic;
        lds_w16h(R1, row, col, (_Float16)(z + b1c));
        lds_w16h(R2, row, col, (_Float16)fast_tanh(z));
      }
  }
  __syncthreads();

  // ---- 4 transport layers ----
#pragma unroll 1
  for (int l = 0; l < 4; ++l) {
    // u' = r1@Pm + r2@Q   (K=512: A = R1 then R2)
#pragma unroll
    for (int t = 0; t < 16; ++t) acc[t] = zero;
    gemm_k<16, true>(PQP + (size_t)l * 131072, R1, R2, acc, w, lane, quad, l16);
    __syncthreads();
    const float* bn = (l == 0) ? b2 : (l == 1) ? b3 : b4;
#pragma unroll
    for (int ni = 0; ni < 8; ++ni) {
      const int col = w * 128 + ni * 16 + l16;
      const float bc = (l < 3) ? DTC * bn[col] : 0.f;
#pragma unroll
      for (int mi = 0; mi < 2; ++mi)
#pragma unroll
        for (int r = 0; r < 4; ++r)
          lds_w16h(R1, mi * 16 + quad * 4 + r, col, (_Float16)(acc[mi * 8 + ni][r] + bc));
    }
    __syncthreads();
    if (l < 3) {
      // r1@Rm ; v' = r1@Rm - crm - r2 ; new r2 = (v' + 10 tanh(u'))/11
#pragma unroll
      for (int t = 0; t < 16; ++t) acc[t] = zero;
      gemm_k<8, false>(RmP + (size_t)l * 65536, R1, R1, acc, w, lane, quad, l16);
      __syncthreads();
#pragma unroll
      for (int ni = 0; ni < 8; ++ni) {
        const int col = w * 128 + ni * 16 + l16;
        const float cc = crm[l * 256 + col];
        const float bc = DTC * bn[col];
#pragma unroll
        for (int mi = 0; mi < 2; ++mi)
#pragma unroll
          for (int r = 0; r < 4; ++r) {
            const int row = mi * 16 + quad * 4 + r;
            const float uv = lds_r16h(R1, row, col) - bc;
            const float r2o = lds_r16h(R2, row, col);
            const float vp = acc[mi * 8 + ni][r] - cc - r2o;
            lds_w16h(R2, row, col, (_Float16)((vp + 10.f * fast_tanh(uv)) * (1.f / 11.f)));
          }
      }
      __syncthreads();
    }
  }

  // ---- head: logits = z@Wo^T + bo (16-padded classes); softmax over 10 ----
  {
    f32x4 acch = zero;
#pragma unroll
    for (int kt = 0; kt < 8; ++kt) {
      const int row = w * 16 + l16;
      const int chunk = (kt * 4 + quad) ^ (row & 7);
      const half8 af = *(const half8*)((const char*)R1 + row * 512 + (chunk << 4));
      const half8 bfr = *(const half8*)&WoP[(kt * 64 + lane) * 8];
      acch = __builtin_amdgcn_mfma_f32_16x16x32_f16(af, bfr, acch, 0, 0, 0);
    }
    const float bov = (l16 < 10) ? bo[l16] : -3.0e38f;
#pragma unroll
    for (int r = 0; r < 4; ++r) {
      float v = acch[r] + bov;
      float mx = v;
#pragma unroll
      for (int off = 1; off < 16; off <<= 1) mx = fmaxf(mx, __shfl_xor(mx, off, 64));
      const float e = __expf(v - mx);
      float s = e;
#pragma unroll
      for (int off = 1; off < 16; off <<= 1) s += __shfl_xor(s, off, 64);
      if (l16 < 10)
        out[(size_t)(m0 + w * 16 + quad * 4 + r) * 10 + l16] = e * __builtin_amdgcn_rcpf(s);
    }
  }
}

// ================= launcher ==================================================

extern "C" void kernel_launch(void* const* d_in, const int* in_sizes, int n_in,
                              void* d_out, int out_size, void* d_ws, size_t ws_size,
                              hipStream_t stream) {
  const float* x  = (const float*)d_in[0];
  const float* Wi = (const float*)d_in[1];
  const float* bi = (const float*)d_in[2];
  const float* W[4] = {(const float*)d_in[3], (const float*)d_in[5],
                       (const float*)d_in[7], (const float*)d_in[9]};
  const float* b[4] = {(const float*)d_in[4], (const float*)d_in[6],
                       (const float*)d_in[8], (const float*)d_in[10]};
  const float* Wo = (const float*)d_in[11];
  const float* bo = (const float*)d_in[12];
  float* out = (float*)d_out;

  const int Bsz = in_sizes[0] / 256;  // 32768

  _Float16* hb = (_Float16*)d_ws;
  _Float16* WiP = hb;                   // 65536
  _Float16* WoP = hb + 65536;           // 4096
  _Float16* PQP = hb + 69632;           // 524288
  _Float16* RmP = hb + 593920;          // 196608
  _Float16* Wh  = hb + 790528;          // 262144
  _Float16* Wt  = hb + 1052672;         // 262144
  _Float16* Eh  = hb + 1314816;         // 262144
  _Float16* Ph  = hb + 1576960;         // 262144
  _Float16* Qt  = hb + 1839104;         // 262144
  float* crm = (float*)(hb + 2101248);  // 768 floats

  const dim3 g64(4, 4, 4);
  k_prep<<<387, 256, 0, stream>>>(W[0], W[1], W[2], W[3], b[1], b[2], b[3],
                                  Wh, Wt, crm);
  k_smm3<<<g64, 256, 0, stream>>>(Wh, Wh, nullptr, Eh, 0.01f, 0);  // E = DT^2 W W^T
  k_smm3<<<g64, 256, 0, stream>>>(Eh, Eh, Eh, Ph, 1.0f, 1);        // P = I - E + E^2
  k_smm3<<<g64, 256, 0, stream>>>(Ph, Wt, nullptr, Qt, DTC, 0);    // Qt = 0.1 P@W
  k_pack<<<386, 256, 0, stream>>>(Ph, Qt, Wt, Wi, Wo, PQP, RmP, WiP, WoP);

  k_fused<<<Bsz / 32, 128, 0, stream>>>(x, WiP, PQP, RmP, WoP, bi,
                                        b[0], b[1], b[2], b[3], crm, bo, out);
}

// Round 7
// 264.022 us; speedup vs baseline: 1.4883x; 1.4883x over previous
//
#include <hip/hip_runtime.h>
#include <math.h>

#define DTC 0.1f

typedef _Float16 half8 __attribute__((ext_vector_type(8)));
typedef float f32x4 __attribute__((ext_vector_type(4)));

__device__ __forceinline__ float fast_tanh(float x) {
  const float e = __expf(2.f * x);
  const float r = __builtin_amdgcn_rcpf(e + 1.f);
  return fmaf(-2.f, r, 1.f);
}

// ================= precompute =================================================

// Wh = fp16(W) ; Wt = fp16(W^T) ; crm[l][j] = -0.09 * sum_k b_{l+2}[k] W_l[k][j]
__global__ __launch_bounds__(256) void k_prep(
    const float* __restrict__ W0, const float* __restrict__ W1,
    const float* __restrict__ W2, const float* __restrict__ W3,
    const float* __restrict__ b2, const float* __restrict__ b3,
    const float* __restrict__ b4,
    _Float16* __restrict__ Wh, _Float16* __restrict__ Wt,
    float* __restrict__ crm) {
  const float* Ws[4] = {W0, W1, W2, W3};
  const int bid = blockIdx.x, tid = threadIdx.x;
  if (bid < 128) {
    const int t = bid * 256 + tid;
    const float* W = Ws[(t * 8) >> 16];
    const int off = (t * 8) & 65535;
    const float4 a = *(const float4*)&W[off];
    const float4 b = *(const float4*)&W[off + 4];
    half8 h;
    h[0] = (_Float16)a.x; h[1] = (_Float16)a.y; h[2] = (_Float16)a.z; h[3] = (_Float16)a.w;
    h[4] = (_Float16)b.x; h[5] = (_Float16)b.y; h[6] = (_Float16)b.z; h[7] = (_Float16)b.w;
    *(half8*)&Wh[t * 8] = h;
  } else if (bid < 384) {
    __shared__ float sh[32][33];
    const int b2i = bid - 128;
    const int l = b2i >> 6, t64 = b2i & 63;
    const int r0 = (t64 >> 3) * 32, c0 = (t64 & 7) * 32;
    const float* W = Ws[l];
    const int i = tid >> 5, j = tid & 31;
#pragma unroll
    for (int p = 0; p < 4; ++p)
      sh[p * 8 + i][j] = W[(r0 + p * 8 + i) * 256 + c0 + j];
    __syncthreads();
#pragma unroll
    for (int p = 0; p < 4; ++p)
      Wt[l * 65536 + (c0 + p * 8 + i) * 256 + r0 + j] = (_Float16)sh[j][p * 8 + i];
  } else {
    const int l = bid - 384;
    const float* W = Ws[l];
    const float* b = (l == 0) ? b2 : (l == 1) ? b3 : b4;
    float s = 0.f;
#pragma unroll 8
    for (int k = 0; k < 256; ++k) s = fmaf(b[k], W[k * 256 + tid], s);
    crm[l * 256 + tid] = -0.09f * s;
  }
}

// C = scale*(A@B^T) [+ I - Eadd]   per layer (blockIdx.z), 256x256, fp16 rm out
__global__ __launch_bounds__(256) void k_smm3(const _Float16* __restrict__ A,
                                              const _Float16* __restrict__ B,
                                              const _Float16* __restrict__ Eadd,
                                              _Float16* __restrict__ C,
                                              float scale, int addI) {
  const int tid = threadIdx.x, wave = tid >> 6, lane = tid & 63;
  const int quad = lane >> 4, l16 = lane & 15;
  const int l = blockIdx.z;
  const _Float16* Al = A + (size_t)l * 65536;
  const _Float16* Bl = B + (size_t)l * 65536;
  _Float16* Cl = C + (size_t)l * 65536;
  const int m0 = blockIdx.y * 64 + wave * 16, n0 = blockIdx.x * 64;
  f32x4 acc[4] = {};
#pragma unroll
  for (int kt = 0; kt < 8; ++kt) {
    const half8 af = *(const half8*)&Al[(m0 + l16) * 256 + kt * 32 + quad * 8];
#pragma unroll
    for (int ni = 0; ni < 4; ++ni) {
      const half8 bf = *(const half8*)&Bl[(n0 + ni * 16 + l16) * 256 + kt * 32 + quad * 8];
      acc[ni] = __builtin_amdgcn_mfma_f32_16x16x32_f16(af, bf, acc[ni], 0, 0, 0);
    }
  }
#pragma unroll
  for (int ni = 0; ni < 4; ++ni)
#pragma unroll
    for (int r = 0; r < 4; ++r) {
      const int row = m0 + quad * 4 + r, col = n0 + ni * 16 + l16;
      float v = scale * acc[ni][r];
      if (addI) v += (row == col ? 1.f : 0.f) - (float)(Eadd + (size_t)l * 65536)[row * 256 + col];
      Cl[row * 256 + col] = (_Float16)v;
    }
}

// Destination-mapped coalesced packing of all B-frag weight buffers.
// packed idx = ((ntile*NKT+kt)*64 + lane)*8 + j
// holds B[n=ntile*16+(lane&15)][k=kt*32+(lane>>4)*8+j]
__global__ __launch_bounds__(256) void k_pack(
    const _Float16* __restrict__ Ph, const _Float16* __restrict__ Qt,
    const _Float16* __restrict__ Wt, const float* __restrict__ Wi,
    const float* __restrict__ Wo,
    _Float16* __restrict__ PQP, _Float16* __restrict__ RmP,
    _Float16* __restrict__ WiP, _Float16* __restrict__ WoP) {
  const int t = blockIdx.x * 256 + threadIdx.x;
  if (t < 65536) {  // PQP: NKT=16, kt<8 -> -P (sym), kt>=8 -> Qt
    const int l = t >> 14, c = t & 16383;
    const int ntile = c >> 10, kt = (c >> 6) & 15, lb = c & 63;
    const int n = ntile * 16 + (lb & 15);
    const int kq = (lb >> 4) * 8;
    half8 h;
    if (kt < 8) {
      h = *(const half8*)&Ph[(size_t)l * 65536 + n * 256 + kt * 32 + kq];
#pragma unroll
      for (int j = 0; j < 8; ++j) h[j] = -h[j];
    } else {
      h = *(const half8*)&Qt[(size_t)l * 65536 + n * 256 + (kt - 8) * 32 + kq];
    }
    *(half8*)&PQP[(size_t)t * 8] = h;
  } else if (t < 90112) {  // RmP: NKT=8, B[n][k] = -0.9*Wt[n][k]
    const int tt = t - 65536;
    const int l = tt >> 13, c = tt & 8191;
    const int ntile = c >> 9, kt = (c >> 6) & 7, lb = c & 63;
    const int n = ntile * 16 + (lb & 15);
    const int k0 = kt * 32 + (lb >> 4) * 8;
    half8 h = *(const half8*)&Wt[(size_t)l * 65536 + n * 256 + k0];
#pragma unroll
    for (int j = 0; j < 8; ++j) h[j] = (_Float16)(-0.9f * (float)h[j]);
    *(half8*)&RmP[(size_t)tt * 8] = h;
  } else if (t < 98304) {  // WiP: NKT=8, B[n][k] = Wi[n][k]
    const int c = t - 90112;
    const int ntile = c >> 9, kt = (c >> 6) & 7, lb = c & 63;
    const int n = ntile * 16 + (lb & 15);
    const int k0 = kt * 32 + (lb >> 4) * 8;
    const float4 a = *(const float4*)&Wi[n * 256 + k0];
    const float4 b = *(const float4*)&Wi[n * 256 + k0 + 4];
    half8 h;
    h[0] = (_Float16)a.x; h[1] = (_Float16)a.y; h[2] = (_Float16)a.z; h[3] = (_Float16)a.w;
    h[4] = (_Float16)b.x; h[5] = (_Float16)b.y; h[6] = (_Float16)b.z; h[7] = (_Float16)b.w;
    *(half8*)&WiP[(size_t)c * 8] = h;
  } else {  // WoP: NKT=8, classes padded to 16
    const int c = t - 98304;  // 0..511
    const int kt = c >> 6, lb = c & 63;
    const int n = lb & 15;
    const int k0 = kt * 32 + (lb >> 4) * 8;
    half8 h;
#pragma unroll
    for (int j = 0; j < 8; ++j) h[j] = (_Float16)((n < 10) ? Wo[n * 256 + k0 + j] : 0.f);
    *(half8*)&WoP[(size_t)c * 8] = h;
  }
}

// ================= fused persistent batch kernel =============================
// 256 threads (4 waves), 64 batch rows/block, wave tile 64x64. r1/r2 in two
// 32 KB LDS slabs (XOR-swizzled). B-frags from L2 with depth-2 static-slot
// prefetch (no dynamic indexing -> no scratch). Next-GEMM B-frags are loaded
// BEFORE the epilogue barriers (global loads, no LDS dependency).

__device__ __forceinline__ void lds_w16h(_Float16* base, int row, int col, _Float16 v) {
  const int chunk = (col >> 3) ^ (row & 7);
  *(_Float16*)((char*)base + row * 512 + (chunk << 4) + (col & 7) * 2) = v;
}
__device__ __forceinline__ float lds_r16h(const _Float16* base, int row, int col) {
  const int chunk = (col >> 3) ^ (row & 7);
  return (float)*(const _Float16*)((const char*)base + row * 512 + (chunk << 4) + (col & 7) * 2);
}

template <int NKT>
__device__ __forceinline__ void loadB2(const _Float16* __restrict__ Bp, int w, int lane,
                                       half8 (&s0)[4], half8 (&s1)[4]) {
#pragma unroll
  for (int ni = 0; ni < 4; ++ni) {
    s0[ni] = *(const half8*)&Bp[(size_t)(((w * 4 + ni) * NKT + 0) * 64 + lane) * 8];
    s1[ni] = *(const half8*)&Bp[(size_t)(((w * 4 + ni) * NKT + 1) * 64 + lane) * 8];
  }
}

// acc[mi*4+ni]; rows mi*16.., cols w*64 + ni*16.. ; s0/s1 pre-loaded kt=0,1
template <int NKT, bool DUAL>
__device__ __forceinline__ void gemm_body(const _Float16* __restrict__ Bp,
                                          const _Float16* __restrict__ Aa,
                                          const _Float16* __restrict__ Ab,
                                          f32x4 (&acc)[16], half8 (&s0)[4], half8 (&s1)[4],
                                          int w, int lane, int quad, int l16) {
#pragma unroll
  for (int kt = 0; kt < NKT; ++kt) {
    half8(&cur)[4] = (kt & 1) ? s1 : s0;
    const _Float16* As = (DUAL && kt >= NKT / 2) ? Ab : Aa;
    const int akt = DUAL ? (kt % (NKT / 2)) : kt;
    half8 af[4];
#pragma unroll
    for (int mi = 0; mi < 4; ++mi) {
      const int row = mi * 16 + l16;
      af[mi] = *(const half8*)((const char*)As + row * 512 +
                               (((akt * 4 + quad) ^ (row & 7)) << 4));
    }
#pragma unroll
    for (int ni = 0; ni < 4; ++ni) {
#pragma unroll
      for (int mi = 0; mi < 4; ++mi)
        acc[mi * 4 + ni] = __builtin_amdgcn_mfma_f32_16x16x32_f16(
            af[mi], cur[ni], acc[mi * 4 + ni], 0, 0, 0);
      if (kt + 2 < NKT)  // reload this slot for kt+2 right after last use
        cur[ni] = *(const half8*)&Bp[(size_t)(((w * 4 + ni) * NKT + kt + 2) * 64 + lane) * 8];
    }
  }
}

__global__ __launch_bounds__(256, 2) void k_fused(
    const float* __restrict__ x, const _Float16* __restrict__ WiP,
    const _Float16* __restrict__ PQP, const _Float16* __restrict__ RmP,
    const _Float16* __restrict__ WoP, const float* __restrict__ bi,
    const float* __restrict__ b1, const float* __restrict__ b2,
    const float* __restrict__ b3, const float* __restrict__ b4,
    const float* __restrict__ crm, const float* __restrict__ bo,
    float* __restrict__ out) {
  __shared__ __align__(16) _Float16 A1[64 * 256];
  __shared__ __align__(16) _Float16 A2[64 * 256];
  const int tid = threadIdx.x;
  const int w = tid >> 6, lane = tid & 63;
  const int quad = lane >> 4, l16 = lane & 15;
  const int m0 = blockIdx.x * 64;

  half8 s0[4], s1[4];
  loadB2<8>(WiP, w, lane, s0, s1);  // prefetch G0 B before x staging barrier

  // ---- stage x: fp32 HBM -> fp16 swizzled LDS (A1) ----
#pragma unroll
  for (int it = 0; it < 16; ++it) {
    const int idx = it * 256 + tid;
    const int row = idx >> 6, c4 = idx & 63;
    const float4 v = *(const float4*)&x[(size_t)(m0 + row) * 256 + c4 * 4];
    const int chunk = (c4 >> 1) ^ (row & 7), part = c4 & 1;
    _Float16* p = (_Float16*)((char*)A1 + row * 512 + (chunk << 4) + (part << 3));
    p[0] = (_Float16)v.x; p[1] = (_Float16)v.y; p[2] = (_Float16)v.z; p[3] = (_Float16)v.w;
  }
  __syncthreads();

  f32x4 acc[16];
  const f32x4 zero = {0.f, 0.f, 0.f, 0.f};

  // ---- G0: z = x@WiT ; A1 = r1 = z+bi+0.1*b1 ; A2 = r2 = tanh(z+bi) ----
#pragma unroll
  for (int t = 0; t < 16; ++t) acc[t] = zero;
  gemm_body<8, false>(WiP, A1, A1, acc, s0, s1, w, lane, quad, l16);
  loadB2<16>(PQP, w, lane, s0, s1);  // prefetch layer-0 G1 across barriers
  __syncthreads();
#pragma unroll
  for (int ni = 0; ni < 4; ++ni) {
    const int col = w * 64 + ni * 16 + l16;
    const float bic = bi[col], b1c = DTC * b1[col];
#pragma unroll
    for (int mi = 0; mi < 4; ++mi)
#pragma unroll
      for (int r = 0; r < 4; ++r) {
        const int row = mi * 16 + quad * 4 + r;
        const float z = acc[mi * 4 + ni][r] + bic;
        lds_w16h(A1, row, col, (_Float16)(z + b1c));
        lds_w16h(A2, row, col, (_Float16)fast_tanh(z));
      }
  }
  __syncthreads();

  // ---- 4 transport layers ----
#pragma unroll 1
  for (int l = 0; l < 4; ++l) {
    // G1: u' = r1@Pm + r2@Q   (K=512: A = A1 then A2)
#pragma unroll
    for (int t = 0; t < 16; ++t) acc[t] = zero;
    gemm_body<16, true>(PQP + (size_t)l * 131072, A1, A2, acc, s0, s1, w, lane, quad, l16);
    if (l < 3) loadB2<8>(RmP + (size_t)l * 65536, w, lane, s0, s1);  // prefetch G2
    __syncthreads();
    const float* bn = (l == 0) ? b2 : (l == 1) ? b3 : b4;
#pragma unroll
    for (int ni = 0; ni < 4; ++ni) {
      const int col = w * 64 + ni * 16 + l16;
      const float bc = (l < 3) ? DTC * bn[col] : 0.f;
#pragma unroll
      for (int mi = 0; mi < 4; ++mi)
#pragma unroll
        for (int r = 0; r < 4; ++r)
          lds_w16h(A1, mi * 16 + quad * 4 + r, col, (_Float16)(acc[mi * 4 + ni][r] + bc));
    }
    __syncthreads();
    if (l < 3) {
      // G2: r1@Rm ; v' = acc - crm - r2 ; new r2 = (v' + 10 tanh(u'))/11
#pragma unroll
      for (int t = 0; t < 16; ++t) acc[t] = zero;
      gemm_body<8, false>(RmP + (size_t)l * 65536, A1, A1, acc, s0, s1, w, lane, quad, l16);
      loadB2<16>(PQP + (size_t)(l + 1) * 131072, w, lane, s0, s1);  // prefetch next G1
#pragma unroll
      for (int ni = 0; ni < 4; ++ni) {
        const int col = w * 64 + ni * 16 + l16;
        const float cc = crm[l * 256 + col];
        const float bc = DTC * bn[col];
#pragma unroll
        for (int mi = 0; mi < 4; ++mi)
#pragma unroll
          for (int r = 0; r < 4; ++r) {
            const int row = mi * 16 + quad * 4 + r;
            const float uv = lds_r16h(A1, row, col) - bc;
            const float r2o = lds_r16h(A2, row, col);
            const float vp = acc[mi * 4 + ni][r] - cc - r2o;
            lds_w16h(A2, row, col, (_Float16)((vp + 10.f * fast_tanh(uv)) * (1.f / 11.f)));
          }
      }
      __syncthreads();
    }
  }

  // ---- head: logits = z@Wo^T + bo (16-padded classes); softmax over 10 ----
  {
    f32x4 acch = zero;
#pragma unroll
    for (int kt = 0; kt < 8; ++kt) {
      const int row = w * 16 + l16;
      const int chunk = (kt * 4 + quad) ^ (row & 7);
      const half8 af = *(const half8*)((const char*)A1 + row * 512 + (chunk << 4));
      const half8 bfr = *(const half8*)&WoP[(kt * 64 + lane) * 8];
      acch = __builtin_amdgcn_mfma_f32_16x16x32_f16(af, bfr, acch, 0, 0, 0);
    }
    const float bov = (l16 < 10) ? bo[l16] : -3.0e38f;
#pragma unroll
    for (int r = 0; r < 4; ++r) {
      float v = acch[r] + bov;
      float mx = v;
#pragma unroll
      for (int off = 1; off < 16; off <<= 1) mx = fmaxf(mx, __shfl_xor(mx, off, 64));
      const float e = __expf(v - mx);
      float s = e;
#pragma unroll
      for (int off = 1; off < 16; off <<= 1) s += __shfl_xor(s, off, 64);
      if (l16 < 10)
        out[(size_t)(m0 + w * 16 + quad * 4 + r) * 10 + l16] = e * __builtin_amdgcn_rcpf(s);
    }
  }
}

// ================= launcher ==================================================

extern "C" void kernel_launch(void* const* d_in, const int* in_sizes, int n_in,
                              void* d_out, int out_size, void* d_ws, size_t ws_size,
                              hipStream_t stream) {
  const float* x  = (const float*)d_in[0];
  const float* Wi = (const float*)d_in[1];
  const float* bi = (const float*)d_in[2];
  const float* W[4] = {(const float*)d_in[3], (const float*)d_in[5],
                       (const float*)d_in[7], (const float*)d_in[9]};
  const float* b[4] = {(const float*)d_in[4], (const float*)d_in[6],
                       (const float*)d_in[8], (const float*)d_in[10]};
  const float* Wo = (const float*)d_in[11];
  const float* bo = (const float*)d_in[12];
  float* out = (float*)d_out;

  const int Bsz = in_sizes[0] / 256;  // 32768

  _Float16* hb = (_Float16*)d_ws;
  _Float16* WiP = hb;                   // 65536
  _Float16* WoP = hb + 65536;           // 4096
  _Float16* PQP = hb + 69632;           // 524288
  _Float16* RmP = hb + 593920;          // 196608
  _Float16* Wh  = hb + 790528;          // 262144
  _Float16* Wt  = hb + 1052672;         // 262144
  _Float16* Eh  = hb + 1314816;         // 262144
  _Float16* Ph  = hb + 1576960;         // 262144
  _Float16* Qt  = hb + 1839104;         // 262144
  float* crm = (float*)(hb + 2101248);  // 768 floats

  const dim3 g64(4, 4, 4);
  k_prep<<<387, 256, 0, stream>>>(W[0], W[1], W[2], W[3], b[1], b[2], b[3],
                                  Wh, Wt, crm);
  k_smm3<<<g64, 256, 0, stream>>>(Wh, Wh, nullptr, Eh, 0.01f, 0);  // E = DT^2 W W^T
  k_smm3<<<g64, 256, 0, stream>>>(Eh, Eh, Eh, Ph, 1.0f, 1);        // P = I - E + E^2
  k_smm3<<<g64, 256, 0, stream>>>(Ph, Wt, nullptr, Qt, DTC, 0);    // Qt = 0.1 P@W
  k_pack<<<386, 256, 0, stream>>>(Ph, Qt, Wt, Wi, Wo, PQP, RmP, WiP, WoP);

  k_fused<<<Bsz / 64, 256, 0, stream>>>(x, WiP, PQP, RmP, WoP, bi,
                                        b[0], b[1], b[2], b[3], crm, bo, out);
}

// Round 8
// 242.073 us; speedup vs baseline: 1.6232x; 1.0907x over previous
//
#include <hip/hip_runtime.h>
#include <math.h>

#define DTC 0.1f

typedef _Float16 half8 __attribute__((ext_vector_type(8)));
typedef float f32x4 __attribute__((ext_vector_type(4)));

__device__ __forceinline__ float fast_tanh(float x) {
  const float e = __expf(2.f * x);
  const float r = __builtin_amdgcn_rcpf(e + 1.f);
  return fmaf(-2.f, r, 1.f);
}

// ================= precompute =================================================

// Wh = fp16(W) ; Wt = fp16(W^T) ; crm[l][j] = -0.09 * sum_k b_{l+2}[k] W_l[k][j]
__global__ __launch_bounds__(256) void k_prep(
    const float* __restrict__ W0, const float* __restrict__ W1,
    const float* __restrict__ W2, const float* __restrict__ W3,
    const float* __restrict__ b2, const float* __restrict__ b3,
    const float* __restrict__ b4,
    _Float16* __restrict__ Wh, _Float16* __restrict__ Wt,
    float* __restrict__ crm) {
  const float* Ws[4] = {W0, W1, W2, W3};
  const int bid = blockIdx.x, tid = threadIdx.x;
  if (bid < 128) {
    const int t = bid * 256 + tid;
    const float* W = Ws[(t * 8) >> 16];
    const int off = (t * 8) & 65535;
    const float4 a = *(const float4*)&W[off];
    const float4 b = *(const float4*)&W[off + 4];
    half8 h;
    h[0] = (_Float16)a.x; h[1] = (_Float16)a.y; h[2] = (_Float16)a.z; h[3] = (_Float16)a.w;
    h[4] = (_Float16)b.x; h[5] = (_Float16)b.y; h[6] = (_Float16)b.z; h[7] = (_Float16)b.w;
    *(half8*)&Wh[t * 8] = h;
  } else if (bid < 384) {
    __shared__ float sh[32][33];
    const int b2i = bid - 128;
    const int l = b2i >> 6, t64 = b2i & 63;
    const int r0 = (t64 >> 3) * 32, c0 = (t64 & 7) * 32;
    const float* W = Ws[l];
    const int i = tid >> 5, j = tid & 31;
#pragma unroll
    for (int p = 0; p < 4; ++p)
      sh[p * 8 + i][j] = W[(r0 + p * 8 + i) * 256 + c0 + j];
    __syncthreads();
#pragma unroll
    for (int p = 0; p < 4; ++p)
      Wt[l * 65536 + (c0 + p * 8 + i) * 256 + r0 + j] = (_Float16)sh[j][p * 8 + i];
  } else {
    const int l = bid - 384;
    const float* W = Ws[l];
    const float* b = (l == 0) ? b2 : (l == 1) ? b3 : b4;
    float s = 0.f;
#pragma unroll 8
    for (int k = 0; k < 256; ++k) s = fmaf(b[k], W[k * 256 + tid], s);
    crm[l * 256 + tid] = -0.09f * s;
  }
}

// C = scale*(A@B^T) [+ I - Eadd]   per layer (blockIdx.z), 256x256, fp16 rm out
__global__ __launch_bounds__(256) void k_smm3(const _Float16* __restrict__ A,
                                              const _Float16* __restrict__ B,
                                              const _Float16* __restrict__ Eadd,
                                              _Float16* __restrict__ C,
                                              float scale, int addI) {
  const int tid = threadIdx.x, wave = tid >> 6, lane = tid & 63;
  const int quad = lane >> 4, l16 = lane & 15;
  const int l = blockIdx.z;
  const _Float16* Al = A + (size_t)l * 65536;
  const _Float16* Bl = B + (size_t)l * 65536;
  _Float16* Cl = C + (size_t)l * 65536;
  const int m0 = blockIdx.y * 64 + wave * 16, n0 = blockIdx.x * 64;
  f32x4 acc[4] = {};
#pragma unroll
  for (int kt = 0; kt < 8; ++kt) {
    const half8 af = *(const half8*)&Al[(m0 + l16) * 256 + kt * 32 + quad * 8];
#pragma unroll
    for (int ni = 0; ni < 4; ++ni) {
      const half8 bf = *(const half8*)&Bl[(n0 + ni * 16 + l16) * 256 + kt * 32 + quad * 8];
      acc[ni] = __builtin_amdgcn_mfma_f32_16x16x32_f16(af, bf, acc[ni], 0, 0, 0);
    }
  }
#pragma unroll
  for (int ni = 0; ni < 4; ++ni)
#pragma unroll
    for (int r = 0; r < 4; ++r) {
      const int row = m0 + quad * 4 + r, col = n0 + ni * 16 + l16;
      float v = scale * acc[ni][r];
      if (addI) v += (row == col ? 1.f : 0.f) - (float)(Eadd + (size_t)l * 65536)[row * 256 + col];
      Cl[row * 256 + col] = (_Float16)v;
    }
}

// Destination-mapped coalesced packing of all B-frag weight buffers.
// packed idx = ((ntile*NKT+kt)*64 + lane)*8 + j
// holds B[n=ntile*16+(lane&15)][k=kt*32+(lane>>4)*8+j]
__global__ __launch_bounds__(256) void k_pack(
    const _Float16* __restrict__ Ph, const _Float16* __restrict__ Qt,
    const _Float16* __restrict__ Wt, const float* __restrict__ Wi,
    const float* __restrict__ Wo,
    _Float16* __restrict__ PQP, _Float16* __restrict__ RmP,
    _Float16* __restrict__ WiP, _Float16* __restrict__ WoP) {
  const int t = blockIdx.x * 256 + threadIdx.x;
  if (t < 65536) {  // PQP: NKT=16, kt<8 -> -P (sym), kt>=8 -> Qt
    const int l = t >> 14, c = t & 16383;
    const int ntile = c >> 10, kt = (c >> 6) & 15, lb = c & 63;
    const int n = ntile * 16 + (lb & 15);
    const int kq = (lb >> 4) * 8;
    half8 h;
    if (kt < 8) {
      h = *(const half8*)&Ph[(size_t)l * 65536 + n * 256 + kt * 32 + kq];
#pragma unroll
      for (int j = 0; j < 8; ++j) h[j] = -h[j];
    } else {
      h = *(const half8*)&Qt[(size_t)l * 65536 + n * 256 + (kt - 8) * 32 + kq];
    }
    *(half8*)&PQP[(size_t)t * 8] = h;
  } else if (t < 90112) {  // RmP: NKT=8, B[n][k] = -0.9*Wt[n][k]
    const int tt = t - 65536;
    const int l = tt >> 13, c = tt & 8191;
    const int ntile = c >> 9, kt = (c >> 6) & 7, lb = c & 63;
    const int n = ntile * 16 + (lb & 15);
    const int k0 = kt * 32 + (lb >> 4) * 8;
    half8 h = *(const half8*)&Wt[(size_t)l * 65536 + n * 256 + k0];
#pragma unroll
    for (int j = 0; j < 8; ++j) h[j] = (_Float16)(-0.9f * (float)h[j]);
    *(half8*)&RmP[(size_t)tt * 8] = h;
  } else if (t < 98304) {  // WiP: NKT=8, B[n][k] = Wi[n][k]
    const int c = t - 90112;
    const int ntile = c >> 9, kt = (c >> 6) & 7, lb = c & 63;
    const int n = ntile * 16 + (lb & 15);
    const int k0 = kt * 32 + (lb >> 4) * 8;
    const float4 a = *(const float4*)&Wi[n * 256 + k0];
    const float4 b = *(const float4*)&Wi[n * 256 + k0 + 4];
    half8 h;
    h[0] = (_Float16)a.x; h[1] = (_Float16)a.y; h[2] = (_Float16)a.z; h[3] = (_Float16)a.w;
    h[4] = (_Float16)b.x; h[5] = (_Float16)b.y; h[6] = (_Float16)b.z; h[7] = (_Float16)b.w;
    *(half8*)&WiP[(size_t)c * 8] = h;
  } else {  // WoP: NKT=8, classes padded to 16
    const int c = t - 98304;  // 0..511
    const int kt = c >> 6, lb = c & 63;
    const int n = lb & 15;
    const int k0 = kt * 32 + (lb >> 4) * 8;
    half8 h;
#pragma unroll
    for (int j = 0; j < 8; ++j) h[j] = (_Float16)((n < 10) ? Wo[n * 256 + k0 + j] : 0.f);
    *(half8*)&WoP[(size_t)c * 8] = h;
  }
}

// ================= fused persistent batch kernel =============================
// 256 threads (4 waves), 32 batch rows/block, wave tile 32x64. r1/r2 in two
// 16 KB LDS slabs (XOR-swizzled). acc[8]=32 VGPR + static 2-slot B prefetch
// (32 VGPR) keeps live set ~85 regs: NO spill at the 128-VGPR allocation.
// 32 KB LDS/block -> 4 blocks/CU co-resident; their barrier/epilogue phases
// interleave, hiding the per-GEMM L2 latency. NO cross-barrier prefetch
// (that's what spilled R6/R7 -- WRITE_SIZE 73 MB).

__device__ __forceinline__ void lds_w16h(_Float16* base, int row, int col, _Float16 v) {
  const int chunk = (col >> 3) ^ (row & 7);
  *(_Float16*)((char*)base + row * 512 + (chunk << 4) + (col & 7) * 2) = v;
}
__device__ __forceinline__ float lds_r16h(const _Float16* base, int row, int col) {
  const int chunk = (col >> 3) ^ (row & 7);
  return (float)*(const _Float16*)((const char*)base + row * 512 + (chunk << 4) + (col & 7) * 2);
}

// acc[mi*4+ni]: rows mi*16.. (mi<2), cols w*64 + ni*16.. (ni<4)
template <int NKT, bool DUAL>
__device__ __forceinline__ void gemm_k(const _Float16* __restrict__ Bp,
                                       const _Float16* __restrict__ Aa,
                                       const _Float16* __restrict__ Ab,
                                       f32x4 (&acc)[8], int w, int lane,
                                       int quad, int l16) {
  half8 s0[4], s1[4];
#pragma unroll
  for (int ni = 0; ni < 4; ++ni) {
    s0[ni] = *(const half8*)&Bp[(size_t)(((w * 4 + ni) * NKT + 0) * 64 + lane) * 8];
    s1[ni] = *(const half8*)&Bp[(size_t)(((w * 4 + ni) * NKT + 1) * 64 + lane) * 8];
  }
#pragma unroll
  for (int kt = 0; kt < NKT; kt += 2) {
    {  // even kt: use s0, then reload s0 for kt+2
      const _Float16* As = (DUAL && kt >= NKT / 2) ? Ab : Aa;
      const int akt = DUAL ? (kt % (NKT / 2)) : kt;
      const int r0 = l16, r1 = 16 + l16;
      const half8 af0 = *(const half8*)((const char*)As + r0 * 512 +
                                        (((akt * 4 + quad) ^ (r0 & 7)) << 4));
      const half8 af1 = *(const half8*)((const char*)As + r1 * 512 +
                                        (((akt * 4 + quad) ^ (r1 & 7)) << 4));
#pragma unroll
      for (int ni = 0; ni < 4; ++ni) {
        acc[ni]     = __builtin_amdgcn_mfma_f32_16x16x32_f16(af0, s0[ni], acc[ni], 0, 0, 0);
        acc[4 + ni] = __builtin_amdgcn_mfma_f32_16x16x32_f16(af1, s0[ni], acc[4 + ni], 0, 0, 0);
        if (kt + 2 < NKT)
          s0[ni] = *(const half8*)&Bp[(size_t)(((w * 4 + ni) * NKT + kt + 2) * 64 + lane) * 8];
      }
    }
    {  // odd kt: use s1, then reload s1 for kt+3
      const int k1 = kt + 1;
      const _Float16* As = (DUAL && k1 >= NKT / 2) ? Ab : Aa;
      const int akt = DUAL ? (k1 % (NKT / 2)) : k1;
      const int r0 = l16, r1 = 16 + l16;
      const half8 af0 = *(const half8*)((const char*)As + r0 * 512 +
                                        (((akt * 4 + quad) ^ (r0 & 7)) << 4));
      const half8 af1 = *(const half8*)((const char*)As + r1 * 512 +
                                        (((akt * 4 + quad) ^ (r1 & 7)) << 4));
#pragma unroll
      for (int ni = 0; ni < 4; ++ni) {
        acc[ni]     = __builtin_amdgcn_mfma_f32_16x16x32_f16(af0, s1[ni], acc[ni], 0, 0, 0);
        acc[4 + ni] = __builtin_amdgcn_mfma_f32_16x16x32_f16(af1, s1[ni], acc[4 + ni], 0, 0, 0);
        if (k1 + 2 < NKT)
          s1[ni] = *(const half8*)&Bp[(size_t)(((w * 4 + ni) * NKT + k1 + 2) * 64 + lane) * 8];
      }
    }
  }
}

__global__ __launch_bounds__(256, 2) void k_fused(
    const float* __restrict__ x, const _Float16* __restrict__ WiP,
    const _Float16* __restrict__ PQP, const _Float16* __restrict__ RmP,
    const _Float16* __restrict__ WoP, const float* __restrict__ bi,
    const float* __restrict__ b1, const float* __restrict__ b2,
    const float* __restrict__ b3, const float* __restrict__ b4,
    const float* __restrict__ crm, const float* __restrict__ bo,
    float* __restrict__ out) {
  __shared__ __align__(16) _Float16 A1[32 * 256];
  __shared__ __align__(16) _Float16 A2[32 * 256];
  const int tid = threadIdx.x;
  const int w = tid >> 6, lane = tid & 63;
  const int quad = lane >> 4, l16 = lane & 15;
  const int m0 = blockIdx.x * 32;

  // ---- stage x: fp32 HBM -> fp16 swizzled LDS (A1), 32 rows ----
#pragma unroll
  for (int it = 0; it < 8; ++it) {
    const int idx = it * 256 + tid;  // 0..2047
    const int row = idx >> 6, c4 = idx & 63;
    const float4 v = *(const float4*)&x[(size_t)(m0 + row) * 256 + c4 * 4];
    const int chunk = (c4 >> 1) ^ (row & 7), part = c4 & 1;
    _Float16* p = (_Float16*)((char*)A1 + row * 512 + (chunk << 4) + (part << 3));
    p[0] = (_Float16)v.x; p[1] = (_Float16)v.y; p[2] = (_Float16)v.z; p[3] = (_Float16)v.w;
  }
  __syncthreads();

  f32x4 acc[8];
  const f32x4 zero = {0.f, 0.f, 0.f, 0.f};

  // ---- G0: z = x@WiT ; A1 = r1 = z+bi+0.1*b1 ; A2 = r2 = tanh(z+bi) ----
#pragma unroll
  for (int t = 0; t < 8; ++t) acc[t] = zero;
  gemm_k<8, false>(WiP, A1, A1, acc, w, lane, quad, l16);
  __syncthreads();
#pragma unroll
  for (int ni = 0; ni < 4; ++ni) {
    const int col = w * 64 + ni * 16 + l16;
    const float bic = bi[col], b1c = DTC * b1[col];
#pragma unroll
    for (int mi = 0; mi < 2; ++mi)
#pragma unroll
      for (int r = 0; r < 4; ++r) {
        const int row = mi * 16 + quad * 4 + r;
        const float z = acc[mi * 4 + ni][r] + bic;
        lds_w16h(A1, row, col, (_Float16)(z + b1c));
        lds_w16h(A2, row, col, (_Float16)fast_tanh(z));
      }
  }
  __syncthreads();

  // ---- 4 transport layers ----
#pragma unroll 1
  for (int l = 0; l < 4; ++l) {
    // G1: u' = r1@Pm + r2@Q   (K=512: A = A1 then A2)
#pragma unroll
    for (int t = 0; t < 8; ++t) acc[t] = zero;
    gemm_k<16, true>(PQP + (size_t)l * 131072, A1, A2, acc, w, lane, quad, l16);
    __syncthreads();
    const float* bn = (l == 0) ? b2 : (l == 1) ? b3 : b4;
#pragma unroll
    for (int ni = 0; ni < 4; ++ni) {
      const int col = w * 64 + ni * 16 + l16;
      const float bc = (l < 3) ? DTC * bn[col] : 0.f;
#pragma unroll
      for (int mi = 0; mi < 2; ++mi)
#pragma unroll
        for (int r = 0; r < 4; ++r)
          lds_w16h(A1, mi * 16 + quad * 4 + r, col, (_Float16)(acc[mi * 4 + ni][r] + bc));
    }
    __syncthreads();
    if (l < 3) {
      // G2: r1@Rm ; v' = acc - crm - r2 ; new r2 = (v' + 10 tanh(u'))/11
#pragma unroll
      for (int t = 0; t < 8; ++t) acc[t] = zero;
      gemm_k<8, false>(RmP + (size_t)l * 65536, A1, A1, acc, w, lane, quad, l16);
#pragma unroll
      for (int ni = 0; ni < 4; ++ni) {
        const int col = w * 64 + ni * 16 + l16;
        const float cc = crm[l * 256 + col];
        const float bc = DTC * bn[col];
#pragma unroll
        for (int mi = 0; mi < 2; ++mi)
#pragma unroll
          for (int r = 0; r < 4; ++r) {
            const int row = mi * 16 + quad * 4 + r;
            const float uv = lds_r16h(A1, row, col) - bc;
            const float r2o = lds_r16h(A2, row, col);
            const float vp = acc[mi * 4 + ni][r] - cc - r2o;
            lds_w16h(A2, row, col, (_Float16)((vp + 10.f * fast_tanh(uv)) * (1.f / 11.f)));
          }
      }
      __syncthreads();
    }
  }

  // ---- head: logits = z@Wo^T + bo (16-padded classes); softmax over 10 ----
  if (w < 2) {
    f32x4 acch = zero;
#pragma unroll
    for (int kt = 0; kt < 8; ++kt) {
      const int row = w * 16 + l16;
      const int chunk = (kt * 4 + quad) ^ (row & 7);
      const half8 af = *(const half8*)((const char*)A1 + row * 512 + (chunk << 4));
      const half8 bfr = *(const half8*)&WoP[(kt * 64 + lane) * 8];
      acch = __builtin_amdgcn_mfma_f32_16x16x32_f16(af, bfr, acch, 0, 0, 0);
    }
    const float bov = (l16 < 10) ? bo[l16] : -3.0e38f;
#pragma unroll
    for (int r = 0; r < 4; ++r) {
      float v = acch[r] + bov;
      float mx = v;
#pragma unroll
      for (int off = 1; off < 16; off <<= 1) mx = fmaxf(mx, __shfl_xor(mx, off, 64));
      const float e = __expf(v - mx);
      float s = e;
#pragma unroll
      for (int off = 1; off < 16; off <<= 1) s += __shfl_xor(s, off, 64);
      if (l16 < 10)
        out[(size_t)(m0 + w * 16 + quad * 4 + r) * 10 + l16] = e * __builtin_amdgcn_rcpf(s);
    }
  }
}

// ================= launcher ==================================================

extern "C" void kernel_launch(void* const* d_in, const int* in_sizes, int n_in,
                              void* d_out, int out_size, void* d_ws, size_t ws_size,
                              hipStream_t stream) {
  const float* x  = (const float*)d_in[0];
  const float* Wi = (const float*)d_in[1];
  const float* bi = (const float*)d_in[2];
  const float* W[4] = {(const float*)d_in[3], (const float*)d_in[5],
                       (const float*)d_in[7], (const float*)d_in[9]};
  const float* b[4] = {(const float*)d_in[4], (const float*)d_in[6],
                       (const float*)d_in[8], (const float*)d_in[10]};
  const float* Wo = (const float*)d_in[11];
  const float* bo = (const float*)d_in[12];
  float* out = (float*)d_out;

  const int Bsz = in_sizes[0] / 256;  // 32768

  _Float16* hb = (_Float16*)d_ws;
  _Float16* WiP = hb;                   // 65536
  _Float16* WoP = hb + 65536;           // 4096
  _Float16* PQP = hb + 69632;           // 524288
  _Float16* RmP = hb + 593920;          // 196608
  _Float16* Wh  = hb + 790528;          // 262144
  _Float16* Wt  = hb + 1052672;         // 262144
  _Float16* Eh  = hb + 1314816;         // 262144
  _Float16* Ph  = hb + 1576960;         // 262144
  _Float16* Qt  = hb + 1839104;         // 262144
  float* crm = (float*)(hb + 2101248);  // 768 floats

  const dim3 g64(4, 4, 4);
  k_prep<<<387, 256, 0, stream>>>(W[0], W[1], W[2], W[3], b[1], b[2], b[3],
                                  Wh, Wt, crm);
  k_smm3<<<g64, 256, 0, stream>>>(Wh, Wh, nullptr, Eh, 0.01f, 0);  // E = DT^2 W W^T
  k_smm3<<<g64, 256, 0, stream>>>(Eh, Eh, Eh, Ph, 1.0f, 1);        // P = I - E + E^2
  k_smm3<<<g64, 256, 0, stream>>>(Ph, Wt, nullptr, Qt, DTC, 0);    // Qt = 0.1 P@W
  k_pack<<<386, 256, 0, stream>>>(Ph, Qt, Wt, Wi, Wo, PQP, RmP, WiP, WoP);

  k_fused<<<Bsz / 32, 256, 0, stream>>>(x, WiP, PQP, RmP, WoP, bi,
                                        b[0], b[1], b[2], b[3], crm, bo, out);
}

// Round 9
// 225.675 us; speedup vs baseline: 1.7411x; 1.0727x over previous
//
#include <hip/hip_runtime.h>
#include <math.h>

#define DTC 0.1f

typedef _Float16 half8 __attribute__((ext_vector_type(8)));
typedef float f32x4 __attribute__((ext_vector_type(4)));

__device__ __forceinline__ float fast_tanh(float x) {
  const float e = __expf(2.f * x);
  const float r = __builtin_amdgcn_rcpf(e + 1.f);
  return fmaf(-2.f, r, 1.f);
}

// ================= precompute =================================================

// Wh = fp16(W) ; Wt = fp16(W^T) ; crm[l][j] = -0.09 * sum_k b_{l+2}[k] W_l[k][j]
__global__ __launch_bounds__(256) void k_prep(
    const float* __restrict__ W0, const float* __restrict__ W1,
    const float* __restrict__ W2, const float* __restrict__ W3,
    const float* __restrict__ b2, const float* __restrict__ b3,
    const float* __restrict__ b4,
    _Float16* __restrict__ Wh, _Float16* __restrict__ Wt,
    float* __restrict__ crm) {
  const float* Ws[4] = {W0, W1, W2, W3};
  const int bid = blockIdx.x, tid = threadIdx.x;
  if (bid < 128) {
    const int t = bid * 256 + tid;
    const float* W = Ws[(t * 8) >> 16];
    const int off = (t * 8) & 65535;
    const float4 a = *(const float4*)&W[off];
    const float4 b = *(const float4*)&W[off + 4];
    half8 h;
    h[0] = (_Float16)a.x; h[1] = (_Float16)a.y; h[2] = (_Float16)a.z; h[3] = (_Float16)a.w;
    h[4] = (_Float16)b.x; h[5] = (_Float16)b.y; h[6] = (_Float16)b.z; h[7] = (_Float16)b.w;
    *(half8*)&Wh[t * 8] = h;
  } else if (bid < 384) {
    __shared__ float sh[32][33];
    const int b2i = bid - 128;
    const int l = b2i >> 6, t64 = b2i & 63;
    const int r0 = (t64 >> 3) * 32, c0 = (t64 & 7) * 32;
    const float* W = Ws[l];
    const int i = tid >> 5, j = tid & 31;
#pragma unroll
    for (int p = 0; p < 4; ++p)
      sh[p * 8 + i][j] = W[(r0 + p * 8 + i) * 256 + c0 + j];
    __syncthreads();
#pragma unroll
    for (int p = 0; p < 4; ++p)
      Wt[l * 65536 + (c0 + p * 8 + i) * 256 + r0 + j] = (_Float16)sh[j][p * 8 + i];
  } else {
    const int l = bid - 384;
    const float* W = Ws[l];
    const float* b = (l == 0) ? b2 : (l == 1) ? b3 : b4;
    float s = 0.f;
#pragma unroll 8
    for (int k = 0; k < 256; ++k) s = fmaf(b[k], W[k * 256 + tid], s);
    crm[l * 256 + tid] = -0.09f * s;
  }
}

// C = scale*(A@B^T) [+ I - Eadd]   per layer (blockIdx.z), 256x256, fp16 rm out
__global__ __launch_bounds__(256) void k_smm3(const _Float16* __restrict__ A,
                                              const _Float16* __restrict__ B,
                                              const _Float16* __restrict__ Eadd,
                                              _Float16* __restrict__ C,
                                              float scale, int addI) {
  const int tid = threadIdx.x, wave = tid >> 6, lane = tid & 63;
  const int quad = lane >> 4, l16 = lane & 15;
  const int l = blockIdx.z;
  const _Float16* Al = A + (size_t)l * 65536;
  const _Float16* Bl = B + (size_t)l * 65536;
  _Float16* Cl = C + (size_t)l * 65536;
  const int m0 = blockIdx.y * 64 + wave * 16, n0 = blockIdx.x * 64;
  f32x4 acc[4] = {};
#pragma unroll
  for (int kt = 0; kt < 8; ++kt) {
    const half8 af = *(const half8*)&Al[(m0 + l16) * 256 + kt * 32 + quad * 8];
#pragma unroll
    for (int ni = 0; ni < 4; ++ni) {
      const half8 bf = *(const half8*)&Bl[(n0 + ni * 16 + l16) * 256 + kt * 32 + quad * 8];
      acc[ni] = __builtin_amdgcn_mfma_f32_16x16x32_f16(af, bf, acc[ni], 0, 0, 0);
    }
  }
#pragma unroll
  for (int ni = 0; ni < 4; ++ni)
#pragma unroll
    for (int r = 0; r < 4; ++r) {
      const int row = m0 + quad * 4 + r, col = n0 + ni * 16 + l16;
      float v = scale * acc[ni][r];
      if (addI) v += (row == col ? 1.f : 0.f) - (float)(Eadd + (size_t)l * 65536)[row * 256 + col];
      Cl[row * 256 + col] = (_Float16)v;
    }
}

// Destination-mapped coalesced packing of all B-frag weight buffers.
// packed idx = ((ntile*NKT+kt)*64 + lane)*8 + j
// holds B[n=ntile*16+(lane&15)][k=kt*32+(lane>>4)*8+j]
__global__ __launch_bounds__(256) void k_pack(
    const _Float16* __restrict__ Ph, const _Float16* __restrict__ Qt,
    const _Float16* __restrict__ Wt, const float* __restrict__ Wi,
    const float* __restrict__ Wo,
    _Float16* __restrict__ PQP, _Float16* __restrict__ RmP,
    _Float16* __restrict__ WiP, _Float16* __restrict__ WoP) {
  const int t = blockIdx.x * 256 + threadIdx.x;
  if (t < 65536) {  // PQP: NKT=16, kt<8 -> -P (sym), kt>=8 -> Qt
    const int l = t >> 14, c = t & 16383;
    const int ntile = c >> 10, kt = (c >> 6) & 15, lb = c & 63;
    const int n = ntile * 16 + (lb & 15);
    const int kq = (lb >> 4) * 8;
    half8 h;
    if (kt < 8) {
      h = *(const half8*)&Ph[(size_t)l * 65536 + n * 256 + kt * 32 + kq];
#pragma unroll
      for (int j = 0; j < 8; ++j) h[j] = -h[j];
    } else {
      h = *(const half8*)&Qt[(size_t)l * 65536 + n * 256 + (kt - 8) * 32 + kq];
    }
    *(half8*)&PQP[(size_t)t * 8] = h;
  } else if (t < 90112) {  // RmP: NKT=8, B[n][k] = -0.9*Wt[n][k]
    const int tt = t - 65536;
    const int l = tt >> 13, c = tt & 8191;
    const int ntile = c >> 9, kt = (c >> 6) & 7, lb = c & 63;
    const int n = ntile * 16 + (lb & 15);
    const int k0 = kt * 32 + (lb >> 4) * 8;
    half8 h = *(const half8*)&Wt[(size_t)l * 65536 + n * 256 + k0];
#pragma unroll
    for (int j = 0; j < 8; ++j) h[j] = (_Float16)(-0.9f * (float)h[j]);
    *(half8*)&RmP[(size_t)tt * 8] = h;
  } else if (t < 98304) {  // WiP: NKT=8, B[n][k] = Wi[n][k]
    const int c = t - 90112;
    const int ntile = c >> 9, kt = (c >> 6) & 7, lb = c & 63;
    const int n = ntile * 16 + (lb & 15);
    const int k0 = kt * 32 + (lb >> 4) * 8;
    const float4 a = *(const float4*)&Wi[n * 256 + k0];
    const float4 b = *(const float4*)&Wi[n * 256 + k0 + 4];
    half8 h;
    h[0] = (_Float16)a.x; h[1] = (_Float16)a.y; h[2] = (_Float16)a.z; h[3] = (_Float16)a.w;
    h[4] = (_Float16)b.x; h[5] = (_Float16)b.y; h[6] = (_Float16)b.z; h[7] = (_Float16)b.w;
    *(half8*)&WiP[(size_t)c * 8] = h;
  } else {  // WoP: NKT=8, classes padded to 16
    const int c = t - 98304;  // 0..511
    const int kt = c >> 6, lb = c & 63;
    const int n = lb & 15;
    const int k0 = kt * 32 + (lb >> 4) * 8;
    half8 h;
#pragma unroll
    for (int j = 0; j < 8; ++j) h[j] = (_Float16)((n < 10) ? Wo[n * 256 + k0 + j] : 0.f);
    *(half8*)&WoP[(size_t)c * 8] = h;
  }
}

// ================= fused persistent batch kernel =============================
// 256 threads (4 waves), 32 batch rows/block, wave tile 32x64. r1/r2 in two
// 16 KB LDS slabs (XOR-swizzled). K-loop is a DYNAMIC #pragma-unroll-1 loop
// over kt-pairs with two static B slots and bumped pointers: the compiler
// cannot hoist loads across iterations, so the live set stays ~95 VGPRs and
// there is no scratch (R4-R8 regressions were all spill-induced; diagnosed
// via WRITE_SIZE >> output bytes). B reload over-reads <=3 KB past each
// packed buffer -- always into the adjacent ws buffer, never unmapped.

__device__ __forceinline__ void lds_w16h(_Float16* base, int row, int col, _Float16 v) {
  const int chunk = (col >> 3) ^ (row & 7);
  *(_Float16*)((char*)base + row * 512 + (chunk << 4) + (col & 7) * 2) = v;
}
__device__ __forceinline__ float lds_r16h(const _Float16* base, int row, int col) {
  const int chunk = (col >> 3) ^ (row & 7);
  return (float)*(const _Float16*)((const char*)base + row * 512 + (chunk << 4) + (col & 7) * 2);
}

// One K=256 pass (8 k-tiles of 32) over A rows [0,32) in LDS slab A,
// B = packed frags at k-tile base kb within an NKTtot-tile buffer.
// acc[mi*4+ni]: rows mi*16+..., cols w*64 + ni*16 + ...
template <int NKTtot>
__device__ __forceinline__ void gemm8(const _Float16* __restrict__ Bp, int kb,
                                      const _Float16* __restrict__ A,
                                      f32x4 (&acc)[8], int w, int lane,
                                      int quad, int l16) {
  const char* bp0 = (const char*)Bp + (size_t)(((w * 4 + 0) * NKTtot + kb) * 64 + lane) * 16;
  const char* bp1 = (const char*)Bp + (size_t)(((w * 4 + 1) * NKTtot + kb) * 64 + lane) * 16;
  const char* bp2 = (const char*)Bp + (size_t)(((w * 4 + 2) * NKTtot + kb) * 64 + lane) * 16;
  const char* bp3 = (const char*)Bp + (size_t)(((w * 4 + 3) * NKTtot + kb) * 64 + lane) * 16;
  half8 s0[4], s1[4];
  s0[0] = *(const half8*)bp0; s0[1] = *(const half8*)bp1;
  s0[2] = *(const half8*)bp2; s0[3] = *(const half8*)bp3;
  s1[0] = *(const half8*)(bp0 + 1024); s1[1] = *(const half8*)(bp1 + 1024);
  s1[2] = *(const half8*)(bp2 + 1024); s1[3] = *(const half8*)(bp3 + 1024);
  const int x = l16 & 7;
  const char* Ab = (const char*)A + l16 * 512;
#pragma unroll 1
  for (int kt2 = 0; kt2 < 4; ++kt2) {
    // even kt = 2*kt2: use s0, then reload s0 for kt+2 (may over-read tail)
    {
      const int c = ((kt2 * 8 + quad) ^ x) << 4;
      const half8 af0 = *(const half8*)(Ab + c);
      const half8 af1 = *(const half8*)(Ab + c + 8192);
      acc[0] = __builtin_amdgcn_mfma_f32_16x16x32_f16(af0, s0[0], acc[0], 0, 0, 0);
      acc[4] = __builtin_amdgcn_mfma_f32_16x16x32_f16(af1, s0[0], acc[4], 0, 0, 0);
      acc[1] = __builtin_amdgcn_mfma_f32_16x16x32_f16(af0, s0[1], acc[1], 0, 0, 0);
      acc[5] = __builtin_amdgcn_mfma_f32_16x16x32_f16(af1, s0[1], acc[5], 0, 0, 0);
      acc[2] = __builtin_amdgcn_mfma_f32_16x16x32_f16(af0, s0[2], acc[2], 0, 0, 0);
      acc[6] = __builtin_amdgcn_mfma_f32_16x16x32_f16(af1, s0[2], acc[6], 0, 0, 0);
      acc[3] = __builtin_amdgcn_mfma_f32_16x16x32_f16(af0, s0[3], acc[3], 0, 0, 0);
      acc[7] = __builtin_amdgcn_mfma_f32_16x16x32_f16(af1, s0[3], acc[7], 0, 0, 0);
      s0[0] = *(const half8*)(bp0 + 2048);
      s0[1] = *(const half8*)(bp1 + 2048);
      s0[2] = *(const half8*)(bp2 + 2048);
      s0[3] = *(const half8*)(bp3 + 2048);
    }
    // odd kt = 2*kt2+1: use s1, then reload s1 for kt+3
    {
      const int c = ((kt2 * 8 + 4 + quad) ^ x) << 4;
      const half8 af0 = *(const half8*)(Ab + c);
      const half8 af1 = *(const half8*)(Ab + c + 8192);
      acc[0] = __builtin_amdgcn_mfma_f32_16x16x32_f16(af0, s1[0], acc[0], 0, 0, 0);
      acc[4] = __builtin_amdgcn_mfma_f32_16x16x32_f16(af1, s1[0], acc[4], 0, 0, 0);
      acc[1] = __builtin_amdgcn_mfma_f32_16x16x32_f16(af0, s1[1], acc[1], 0, 0, 0);
      acc[5] = __builtin_amdgcn_mfma_f32_16x16x32_f16(af1, s1[1], acc[5], 0, 0, 0);
      acc[2] = __builtin_amdgcn_mfma_f32_16x16x32_f16(af0, s1[2], acc[2], 0, 0, 0);
      acc[6] = __builtin_amdgcn_mfma_f32_16x16x32_f16(af1, s1[2], acc[6], 0, 0, 0);
      acc[3] = __builtin_amdgcn_mfma_f32_16x16x32_f16(af0, s1[3], acc[3], 0, 0, 0);
      acc[7] = __builtin_amdgcn_mfma_f32_16x16x32_f16(af1, s1[3], acc[7], 0, 0, 0);
      s1[0] = *(const half8*)(bp0 + 3072);
      s1[1] = *(const half8*)(bp1 + 3072);
      s1[2] = *(const half8*)(bp2 + 3072);
      s1[3] = *(const half8*)(bp3 + 3072);
    }
    bp0 += 2048; bp1 += 2048; bp2 += 2048; bp3 += 2048;
  }
}

__global__ __launch_bounds__(256, 3) void k_fused(
    const float* __restrict__ x, const _Float16* __restrict__ WiP,
    const _Float16* __restrict__ PQP, const _Float16* __restrict__ RmP,
    const _Float16* __restrict__ WoP, const float* __restrict__ bi,
    const float* __restrict__ b1, const float* __restrict__ b2,
    const float* __restrict__ b3, const float* __restrict__ b4,
    const float* __restrict__ crm, const float* __restrict__ bo,
    float* __restrict__ out) {
  __shared__ __align__(16) _Float16 A1[32 * 256];
  __shared__ __align__(16) _Float16 A2[32 * 256];
  const int tid = threadIdx.x;
  const int w = tid >> 6, lane = tid & 63;
  const int quad = lane >> 4, l16 = lane & 15;
  const int m0 = blockIdx.x * 32;

  // ---- stage x: fp32 HBM -> fp16 swizzled LDS (A1), 32 rows ----
#pragma unroll
  for (int it = 0; it < 8; ++it) {
    const int idx = it * 256 + tid;  // 0..2047
    const int row = idx >> 6, c4 = idx & 63;
    const float4 v = *(const float4*)&x[(size_t)(m0 + row) * 256 + c4 * 4];
    const int chunk = (c4 >> 1) ^ (row & 7), part = c4 & 1;
    _Float16* p = (_Float16*)((char*)A1 + row * 512 + (chunk << 4) + (part << 3));
    p[0] = (_Float16)v.x; p[1] = (_Float16)v.y; p[2] = (_Float16)v.z; p[3] = (_Float16)v.w;
  }
  __syncthreads();

  f32x4 acc[8];
  const f32x4 zero = {0.f, 0.f, 0.f, 0.f};

  // ---- G0: z = x@WiT ; A1 = r1 = z+bi+0.1*b1 ; A2 = r2 = tanh(z+bi) ----
#pragma unroll
  for (int t = 0; t < 8; ++t) acc[t] = zero;
  gemm8<8>(WiP, 0, A1, acc, w, lane, quad, l16);
  __syncthreads();
#pragma unroll
  for (int ni = 0; ni < 4; ++ni) {
    const int col = w * 64 + ni * 16 + l16;
    const float bic = bi[col], b1c = DTC * b1[col];
#pragma unroll
    for (int mi = 0; mi < 2; ++mi)
#pragma unroll
      for (int r = 0; r < 4; ++r) {
        const int row = mi * 16 + quad * 4 + r;
        const float z = acc[mi * 4 + ni][r] + bic;
        lds_w16h(A1, row, col, (_Float16)(z + b1c));
        lds_w16h(A2, row, col, (_Float16)fast_tanh(z));
      }
  }
  __syncthreads();

  // ---- 4 transport layers ----
#pragma unroll 1
  for (int l = 0; l < 4; ++l) {
    // G1: u' = r1@Pm + r2@Q   (K=512 = two K=256 passes: A1 then A2)
#pragma unroll
    for (int t = 0; t < 8; ++t) acc[t] = zero;
    const _Float16* PQl = PQP + (size_t)l * 131072;
    gemm8<16>(PQl, 0, A1, acc, w, lane, quad, l16);
    gemm8<16>(PQl, 8, A2, acc, w, lane, quad, l16);
    __syncthreads();
    const float* bn = (l == 0) ? b2 : (l == 1) ? b3 : b4;
#pragma unroll
    for (int ni = 0; ni < 4; ++ni) {
      const int col = w * 64 + ni * 16 + l16;
      const float bc = (l < 3) ? DTC * bn[col] : 0.f;
#pragma unroll
      for (int mi = 0; mi < 2; ++mi)
#pragma unroll
        for (int r = 0; r < 4; ++r)
          lds_w16h(A1, mi * 16 + quad * 4 + r, col, (_Float16)(acc[mi * 4 + ni][r] + bc));
    }
    __syncthreads();
    if (l < 3) {
      // G2: r1@Rm ; v' = acc - crm - r2 ; new r2 = (v' + 10 tanh(u'))/11
#pragma unroll
      for (int t = 0; t < 8; ++t) acc[t] = zero;
      gemm8<8>(RmP + (size_t)l * 65536, 0, A1, acc, w, lane, quad, l16);
#pragma unroll
      for (int ni = 0; ni < 4; ++ni) {
        const int col = w * 64 + ni * 16 + l16;
        const float cc = crm[l * 256 + col];
        const float bc = DTC * bn[col];
#pragma unroll
        for (int mi = 0; mi < 2; ++mi)
#pragma unroll
          for (int r = 0; r < 4; ++r) {
            const int row = mi * 16 + quad * 4 + r;
            const float uv = lds_r16h(A1, row, col) - bc;
            const float r2o = lds_r16h(A2, row, col);
            const float vp = acc[mi * 4 + ni][r] - cc - r2o;
            lds_w16h(A2, row, col, (_Float16)((vp + 10.f * fast_tanh(uv)) * (1.f / 11.f)));
          }
      }
      __syncthreads();
    }
  }

  // ---- head: logits = z@Wo^T + bo (16-padded classes); softmax over 10 ----
  if (w < 2) {
    f32x4 acch = zero;
#pragma unroll
    for (int kt = 0; kt < 8; ++kt) {
      const int row = w * 16 + l16;
      const int chunk = (kt * 4 + quad) ^ (row & 7);
      const half8 af = *(const half8*)((const char*)A1 + row * 512 + (chunk << 4));
      const half8 bfr = *(const half8*)&WoP[(kt * 64 + lane) * 8];
      acch = __builtin_amdgcn_mfma_f32_16x16x32_f16(af, bfr, acch, 0, 0, 0);
    }
    const float bov = (l16 < 10) ? bo[l16] : -3.0e38f;
#pragma unroll
    for (int r = 0; r < 4; ++r) {
      float v = acch[r] + bov;
      float mx = v;
#pragma unroll
      for (int off = 1; off < 16; off <<= 1) mx = fmaxf(mx, __shfl_xor(mx, off, 64));
      const float e = __expf(v - mx);
      float s = e;
#pragma unroll
      for (int off = 1; off < 16; off <<= 1) s += __shfl_xor(s, off, 64);
      if (l16 < 10)
        out[(size_t)(m0 + w * 16 + quad * 4 + r) * 10 + l16] = e * __builtin_amdgcn_rcpf(s);
    }
  }
}

// ================= launcher ==================================================

extern "C" void kernel_launch(void* const* d_in, const int* in_sizes, int n_in,
                              void* d_out, int out_size, void* d_ws, size_t ws_size,
                              hipStream_t stream) {
  const float* x  = (const float*)d_in[0];
  const float* Wi = (const float*)d_in[1];
  const float* bi = (const float*)d_in[2];
  const float* W[4] = {(const float*)d_in[3], (const float*)d_in[5],
                       (const float*)d_in[7], (const float*)d_in[9]};
  const float* b[4] = {(const float*)d_in[4], (const float*)d_in[6],
                       (const float*)d_in[8], (const float*)d_in[10]};
  const float* Wo = (const float*)d_in[11];
  const float* bo = (const float*)d_in[12];
  float* out = (float*)d_out;

  const int Bsz = in_sizes[0] / 256;  // 32768

  _Float16* hb = (_Float16*)d_ws;
  _Float16* WiP = hb;                   // 65536
  _Float16* WoP = hb + 65536;           // 4096
  _Float16* PQP = hb + 69632;           // 524288
  _Float16* RmP = hb + 593920;          // 196608
  _Float16* Wh  = hb + 790528;          // 262144
  _Float16* Wt  = hb + 1052672;         // 262144
  _Float16* Eh  = hb + 1314816;         // 262144
  _Float16* Ph  = hb + 1576960;         // 262144
  _Float16* Qt  = hb + 1839104;         // 262144
  float* crm = (float*)(hb + 2101248);  // 768 floats

  const dim3 g64(4, 4, 4);
  k_prep<<<387, 256, 0, stream>>>(W[0], W[1], W[2], W[3], b[1], b[2], b[3],
                                  Wh, Wt, crm);
  k_smm3<<<g64, 256, 0, stream>>>(Wh, Wh, nullptr, Eh, 0.01f, 0);  // E = DT^2 W W^T
  k_smm3<<<g64, 256, 0, stream>>>(Eh, Eh, Eh, Ph, 1.0f, 1);        // P = I - E + E^2
  k_smm3<<<g64, 256, 0, stream>>>(Ph, Wt, nullptr, Qt, DTC, 0);    // Qt = 0.1 P@W
  k_pack<<<386, 256, 0, stream>>>(Ph, Qt, Wt, Wi, Wo, PQP, RmP, WiP, WoP);

  k_fused<<<Bsz / 32, 256, 0, stream>>>(x, WiP, PQP, RmP, WoP, bi,
                                        b[0], b[1], b[2], b[3], crm, bo, out);
}